// Round 23
// baseline (137.099 us; speedup 1.0000x reference)
//
#include <hip/hip_runtime.h>
#include <hip/hip_bf16.h>

typedef __attribute__((ext_vector_type(8))) short s8v;   // 8 x bf16
typedef __attribute__((ext_vector_type(4))) float f32x4; // MFMA acc

__device__ __forceinline__ float sigf(float x) { return 1.0f / (1.0f + __expf(-x)); }
__device__ __forceinline__ float tanh_fast(float x) { return 1.0f - 2.0f / (1.0f + __expf(2.0f * x)); }
__device__ __forceinline__ ushort f2bf(float f) {
    union { __hip_bfloat16 b; ushort u; } v; v.b = __float2bfloat16(f); return v.u;
}

// Warm this XCD's L2 with the full Bpack (256 KB) using max memory-level parallelism.
// L2 is invalidated at each kernel launch (XCD non-coherence), so without this the
// first stage streams B from HBM through dependent 8-deep chains (R22: mega3 = 42.5us,
// FETCH_SIZE == Bpack size). 512 threads x 32 independent 16B loads; asm keeps them live.
__device__ __forceinline__ void prefetch_B(const ushort* __restrict__ Bpack) {
    const int tid = threadIdx.x;
    #pragma unroll
    for (int it = 0; it < 32; ++it) {
        s8v v = *(const s8v*)(Bpack + ((size_t)tid + 512 * it) * 8);
        asm volatile("" :: "v"(v));
    }
}

// ---------------- prepass (R22-proven) ----------------
__global__ __launch_bounds__(256) void prepass(
    const int* __restrict__ nt, const float* __restrict__ na,
    const float* __restrict__ emb,
    const float* __restrict__ Wih, const float* __restrict__ Whh,
    const float* __restrict__ bih, const float* __restrict__ bhh,
    ushort* __restrict__ Bpack, float4* __restrict__ PX4, float4* __restrict__ Wcol4,
    ushort* __restrict__ HLEAF, float* __restrict__ CLEAF, float2* __restrict__ NC)
{
    const int bx = blockIdx.x;
    const int tid = threadIdx.x;
    if (bx < 64) {
        const int gid = bx * 256 + tid;     // (ty, j)
        const int ty = gid >> 7;
        const int j  = gid & 127;
        const float* e = emb + (size_t)ty * 128;
        float d[4];
        #pragma unroll
        for (int g = 0; g < 4; ++g) {
            const int row = g * 256 + j;
            const float* wr = Wih + (size_t)row * 128;
            float acc = bih[row] + bhh[row];
            #pragma unroll 8
            for (int k = 0; k < 128; k += 4) {
                float4 ev = *(const float4*)(e + k);
                float4 wv = *(const float4*)(wr + k);
                acc = fmaf(ev.x, wv.x, acc); acc = fmaf(ev.y, wv.y, acc);
                acc = fmaf(ev.z, wv.z, acc); acc = fmaf(ev.w, wv.w, acc);
            }
            d[g] = acc;
        }
        PX4[gid] = make_float4(d[0], d[1], d[2], d[3]);
        const float cn = sigf(d[0]) * tanh_fast(d[2]);
        CLEAF[gid] = cn;
        HLEAF[gid] = f2bf(sigf(d[3]) * tanh_fast(cn));
        if (ty == 0)
            Wcol4[j] = make_float4(Wih[(size_t)j * 128 + 127],
                                   Wih[(size_t)(256 + j) * 128 + 127],
                                   Wih[(size_t)(512 + j) * 128 + 127],
                                   Wih[(size_t)(768 + j) * 128 + 127]);
    } else if (bx < 128) {
        const int gid = (bx - 64) * 256 + tid;   // Bpack (Whh only, K=256)
        const int nl  = gid & 127;
        const int seg = (gid >> 7) & 3;
        const int rest = gid >> 9;
        const int kk = rest & 7;
        const int bn = rest >> 3;
        const int g  = (nl >> 4) & 3;
        const int j  = bn * 32 + ((nl >> 6) << 4) + (nl & 15);
        const int row = g * 256 + j;
        const int k = kk * 32 + seg * 8;
        const float* src = Whh + (size_t)row * 256 + k;
        float4 w0 = *(const float4*)(src);
        float4 w1 = *(const float4*)(src + 4);
        ushort o[8] = { f2bf(w0.x), f2bf(w0.y), f2bf(w0.z), f2bf(w0.w),
                        f2bf(w1.x), f2bf(w1.y), f2bf(w1.z), f2bf(w1.w) };
        *(s8v*)(Bpack + (size_t)gid * 8) = *(const s8v*)o;
    } else {
        const int node = (bx - 128) * 256 + tid;
        if (node < 65535) {
            const int ty = nt[node];
            float corr = 0.0f;
            if (ty == 1) corr = na[node] - emb[255];
            else if (ty == 2) corr = na[node] - emb[383];
            NC[node] = make_float2((float)ty, corr);
        }
    }
}

// ================= 8-wave helpers (R22-proven) =================
__device__ __forceinline__ void gemm64_g(
    int rowbase, int nRows, int startL,
    const float2* __restrict__ NC,
    const ushort* __restrict__ h_in, const float* __restrict__ c_in,
    const ushort* __restrict__ Bpack, const float4* __restrict__ PX4,
    const float4* __restrict__ Wcol4,
    ushort (*hO)[136], float (*cO)[132])
{
    const int tid  = threadIdx.x;
    const int lane = tid & 63;
    const int wave = tid >> 6;
    const int wm2 = wave >> 2;
    const int bn  = wave & 3;
    const int lc = lane & 15, seg = lane >> 4;
    const int koff = seg * 8;

    const ushort* ph[2][2];
    #pragma unroll
    for (int mi = 0; mi < 2; ++mi) {
        int mloc = wm2 * 32 + mi * 16 + lc;
        int dg = rowbase + mloc;
        int dgc = dg < nRows ? dg : nRows - 1;
        ph[mi][0] = h_in + (size_t)(2 * dgc) * 128 + koff;
        ph[mi][1] = h_in + (size_t)(2 * dgc + 1) * 128 + koff;
    }
    const ushort* pb = Bpack + (size_t)bn * 32768 + (size_t)seg * 1024
                             + (size_t)lc * 8;

    f32x4 acc[2][8];
    #pragma unroll
    for (int mi = 0; mi < 2; ++mi)
        #pragma unroll
        for (int f = 0; f < 8; ++f) acc[mi][f] = (f32x4){0.f, 0.f, 0.f, 0.f};

    #pragma unroll
    for (int kk = 0; kk < 8; ++kk) {
        const int hi = kk >> 2, off = (kk & 3) * 32;
        s8v a0 = *(const s8v*)(ph[0][hi] + off);
        s8v a1 = *(const s8v*)(ph[1][hi] + off);
        #pragma unroll
        for (int f = 0; f < 8; ++f) {
            s8v bb = *(const s8v*)(pb + (size_t)kk * 4096 + f * 128);
            acc[0][f] = __builtin_amdgcn_mfma_f32_16x16x32_bf16(a0, bb, acc[0][f], 0, 0, 0);
            acc[1][f] = __builtin_amdgcn_mfma_f32_16x16x32_bf16(a1, bb, acc[1][f], 0, 0, 0);
        }
    }
    #pragma unroll
    for (int bh = 0; bh < 2; ++bh) {
        const int j = bn * 32 + bh * 16 + lc;
        const float4 wc = Wcol4[j];
        #pragma unroll
        for (int mi = 0; mi < 2; ++mi) {
            #pragma unroll
            for (int r = 0; r < 4; ++r) {
                const int mloc = wm2 * 32 + mi * 16 + seg * 4 + r;
                const int dg = rowbase + mloc;
                if (dg < nRows) {
                    const float2 nc = NC[startL + dg];
                    const int ty = (int)nc.x;
                    const float corr = nc.y;
                    const float4 px = PX4[(size_t)ty * 128 + j];
                    const float gi = acc[mi][bh * 4 + 0][r] + px.x + corr * wc.x;
                    const float gf = acc[mi][bh * 4 + 1][r] + px.y + corr * wc.y;
                    const float gg = acc[mi][bh * 4 + 2][r] + px.z + corr * wc.z;
                    const float go = acc[mi][bh * 4 + 3][r] + px.w + corr * wc.w;
                    const float c0 = c_in[(size_t)dg * 128 + j];
                    const float cn = sigf(gf) * c0 + sigf(gi) * tanh_fast(gg);
                    const float hn = sigf(go) * tanh_fast(cn);
                    hO[mloc][j] = f2bf(hn);
                    if (!(mloc & 1)) cO[mloc >> 1][j] = cn;
                }
            }
        }
    }
}

__device__ __forceinline__ void gemm64_l(
    int startL, int gbase,
    const float2* __restrict__ NC,
    const ushort (*hIn)[136], const float (*cIn)[132],
    const ushort* __restrict__ Bpack, const float4* __restrict__ PX4,
    const float4* __restrict__ Wcol4,
    ushort (*hO)[136], float (*cO)[132])
{
    const int tid  = threadIdx.x;
    const int lane = tid & 63;
    const int wave = tid >> 6;
    const int wm2 = wave >> 2;
    const int bn  = wave & 3;
    const int lc = lane & 15, seg = lane >> 4;
    const int koff = seg * 8;

    const int m0 = wm2 * 32 + lc;
    const int m1 = m0 + 16;
    const ushort* pb = Bpack + (size_t)bn * 32768 + (size_t)seg * 1024
                             + (size_t)lc * 8;

    f32x4 acc[2][8];
    #pragma unroll
    for (int mi = 0; mi < 2; ++mi)
        #pragma unroll
        for (int f = 0; f < 8; ++f) acc[mi][f] = (f32x4){0.f, 0.f, 0.f, 0.f};

    #pragma unroll
    for (int kk = 0; kk < 8; ++kk) {
        const int hi = kk >> 2, off = (kk & 3) * 32;
        s8v a0 = *(const s8v*)(&hIn[2 * m0 + hi][off + koff]);
        s8v a1 = *(const s8v*)(&hIn[2 * m1 + hi][off + koff]);
        #pragma unroll
        for (int f = 0; f < 8; ++f) {
            s8v bb = *(const s8v*)(pb + (size_t)kk * 4096 + f * 128);
            acc[0][f] = __builtin_amdgcn_mfma_f32_16x16x32_bf16(a0, bb, acc[0][f], 0, 0, 0);
            acc[1][f] = __builtin_amdgcn_mfma_f32_16x16x32_bf16(a1, bb, acc[1][f], 0, 0, 0);
        }
    }
    #pragma unroll
    for (int bh = 0; bh < 2; ++bh) {
        const int j = bn * 32 + bh * 16 + lc;
        const float4 wc = Wcol4[j];
        #pragma unroll
        for (int mi = 0; mi < 2; ++mi) {
            #pragma unroll
            for (int r = 0; r < 4; ++r) {
                const int mloc = wm2 * 32 + mi * 16 + seg * 4 + r;
                const float2 nc = NC[startL + gbase + mloc];
                const int ty = (int)nc.x;
                const float corr = nc.y;
                const float4 px = PX4[(size_t)ty * 128 + j];
                const float gi = acc[mi][bh * 4 + 0][r] + px.x + corr * wc.x;
                const float gf = acc[mi][bh * 4 + 1][r] + px.y + corr * wc.y;
                const float gg = acc[mi][bh * 4 + 2][r] + px.z + corr * wc.z;
                const float go = acc[mi][bh * 4 + 3][r] + px.w + corr * wc.w;
                const float c0 = cIn[mloc][j];
                const float cn = sigf(gf) * c0 + sigf(gi) * tanh_fast(gg);
                const float hn = sigf(go) * tanh_fast(cn);
                hO[mloc][j] = f2bf(hn);
                if (!(mloc & 1)) cO[mloc >> 1][j] = cn;
            }
        }
    }
}

template<int OUT>
__device__ __forceinline__ void gemm32_l(
    int gbase, int nloc, int startL,
    const float2* __restrict__ NC,
    const ushort (*hIn)[136], const float (*cIn)[132],
    const ushort* __restrict__ Bpack, const float4* __restrict__ PX4,
    const float4* __restrict__ Wcol4,
    ushort* __restrict__ h_out, float* __restrict__ c_out,
    ushort (*hOL)[136], float (*cOL)[132], float* hs)
{
    const int tid  = threadIdx.x;
    const int lane = tid & 63;
    const int wave = tid >> 6;
    const int bn = wave >> 1, wn = wave & 1;
    const int lc = lane & 15, seg = lane >> 4;
    const int koff = seg * 8;

    int mcl[2];
    #pragma unroll
    for (int mi = 0; mi < 2; ++mi) {
        int m = mi * 16 + lc;
        mcl[mi] = m < nloc ? m : nloc - 1;
    }
    const ushort* pb = Bpack + (size_t)bn * 32768 + (size_t)seg * 1024
                             + (size_t)(wn * 64 + lc) * 8;

    f32x4 acc[2][4];
    #pragma unroll
    for (int mi = 0; mi < 2; ++mi)
        #pragma unroll
        for (int f = 0; f < 4; ++f) acc[mi][f] = (f32x4){0.f, 0.f, 0.f, 0.f};

    #pragma unroll
    for (int kk = 0; kk < 8; ++kk) {
        const int hi = kk >> 2, off = (kk & 3) * 32;
        s8v a0 = *(const s8v*)(&hIn[2 * mcl[0] + hi][off + koff]);
        s8v a1 = *(const s8v*)(&hIn[2 * mcl[1] + hi][off + koff]);
        #pragma unroll
        for (int f = 0; f < 4; ++f) {
            s8v bb = *(const s8v*)(pb + (size_t)kk * 4096 + f * 128);
            acc[0][f] = __builtin_amdgcn_mfma_f32_16x16x32_bf16(a0, bb, acc[0][f], 0, 0, 0);
            acc[1][f] = __builtin_amdgcn_mfma_f32_16x16x32_bf16(a1, bb, acc[1][f], 0, 0, 0);
        }
    }

    const int j = bn * 32 + wn * 16 + lc;
    const float4 wc = Wcol4[j];
    #pragma unroll
    for (int mi = 0; mi < 2; ++mi) {
        #pragma unroll
        for (int r = 0; r < 4; ++r) {
            const int m = mi * 16 + seg * 4 + r;
            if (m < nloc) {
                const int mPg = gbase + m;
                const float2 nc = NC[startL + mPg];
                const int ty = (int)nc.x;
                const float corr = nc.y;
                const float4 px = PX4[(size_t)ty * 128 + j];
                const float gi = acc[mi][0][r] + px.x + corr * wc.x;
                const float gf = acc[mi][1][r] + px.y + corr * wc.y;
                const float gg = acc[mi][2][r] + px.z + corr * wc.z;
                const float go = acc[mi][3][r] + px.w + corr * wc.w;
                const float c0 = cIn[m][j];
                const float cn = sigf(gf) * c0 + sigf(gi) * tanh_fast(gg);
                const float hn = sigf(go) * tanh_fast(cn);
                if (OUT == 0) {
                    h_out[(size_t)mPg * 128 + j] = f2bf(hn);
                    if (!(mPg & 1)) c_out[(size_t)(mPg >> 1) * 128 + j] = cn;
                } else if (OUT == 1) {
                    hOL[m][j] = f2bf(hn);
                    if (!(m & 1)) cOL[m >> 1][j] = cn;
                } else {
                    hs[j] = hn;
                }
            }
        }
    }
}

// ---------------- mega1: levels 15..12, 256 blocks x 512 (R22-proven) ----------------
__global__ __launch_bounds__(512) void mega1(
    const float2* __restrict__ NC,
    const ushort* __restrict__ Bpack, const float4* __restrict__ PX4,
    const float4* __restrict__ Wcol4,
    const ushort* __restrict__ HLEAF, const float* __restrict__ CLEAF,
    ushort* __restrict__ h_out, float* __restrict__ c_out)   // level-12
{
    __shared__ __align__(16) ushort hD[128][136];
    __shared__ float cD[64][132];
    __shared__ __align__(16) ushort hM[64][136];
    __shared__ float cM[32][132];

    const int tid = threadIdx.x;
    const int b = blockIdx.x;

    {
        const int mloc = tid >> 2;   // 0..127
        const int p4   = tid & 3;    // 32-elem chunk
        const int node = 32767 + 128 * b + mloc;
        const float2 nc = NC[node];
        const int ty = (int)nc.x;
        if (ty != 1 && ty != 2) {
            #pragma unroll
            for (int q = 0; q < 4; ++q)
                *(s8v*)(&hD[mloc][p4 * 32 + q * 8]) =
                    *(const s8v*)(HLEAF + (size_t)ty * 128 + p4 * 32 + q * 8);
            if (!(mloc & 1)) {
                const float4* cr = (const float4*)(CLEAF + (size_t)ty * 128 + p4 * 32);
                float4* cw = (float4*)(&cD[mloc >> 1][p4 * 32]);
                #pragma unroll
                for (int q = 0; q < 8; ++q) cw[q] = cr[q];
            }
        } else {
            const float corr = nc.y;
            #pragma unroll
            for (int q = 0; q < 32; ++q) {
                const int jj = p4 * 32 + q;
                const float4 px = PX4[(size_t)ty * 128 + jj];
                const float4 wc = Wcol4[jj];
                const float gi = px.x + corr * wc.x;
                const float gg = px.z + corr * wc.z;
                const float go = px.w + corr * wc.w;
                const float cn = sigf(gi) * tanh_fast(gg);
                const float hn = sigf(go) * tanh_fast(cn);
                hD[mloc][jj] = f2bf(hn);
                if (!(mloc & 1)) cD[mloc >> 1][jj] = cn;
            }
        }
    }
    __syncthreads();
    gemm64_l(16383, 64 * b, NC, hD, cD, Bpack, PX4, Wcol4, hM, cM);   // L14
    __syncthreads();
    gemm32_l<1>(32 * b, 32, 8191, NC, hM, cM, Bpack, PX4, Wcol4,
                nullptr, nullptr, hD, cD, nullptr);                    // L13
    __syncthreads();
    gemm32_l<0>(16 * b, 16, 4095, NC, hD, cD, Bpack, PX4, Wcol4,
                h_out, c_out, nullptr, nullptr, nullptr);              // L12 -> global
}

// ---------------- mega2: levels 11..6, 32 blocks x 512 (+prefetch) ----------------
__global__ __launch_bounds__(512) void mega2(
    const float2* __restrict__ NC,
    const ushort* __restrict__ Bpack, const float4* __restrict__ PX4,
    const float4* __restrict__ Wcol4,
    const ushort* __restrict__ h_in, const float* __restrict__ c_in,   // level-12
    ushort* __restrict__ h_out, float* __restrict__ c_out)             // level-6
{
    __shared__ __align__(16) ushort hD[64][136];
    __shared__ float cD[32][132];
    __shared__ __align__(16) ushort hM[32][136];
    __shared__ float cM[16][132];

    const int b = blockIdx.x;

    prefetch_B(Bpack);
    gemm64_g(64 * b, 2048, 2047, NC, h_in, c_in,
             Bpack, PX4, Wcol4, hD, cD);                               // L11
    __syncthreads();
    gemm32_l<1>(32 * b, 32, 1023, NC, hD, cD, Bpack, PX4, Wcol4,
                nullptr, nullptr, hM, cM, nullptr);                    // L10
    __syncthreads();
    gemm32_l<1>(16 * b, 16, 511, NC, hM, cM, Bpack, PX4, Wcol4,
                nullptr, nullptr, hD, cD, nullptr);                    // L9
    __syncthreads();
    gemm32_l<1>(8 * b, 8, 255, NC, hD, cD, Bpack, PX4, Wcol4,
                nullptr, nullptr, hM, cM, nullptr);                    // L8
    __syncthreads();
    gemm32_l<1>(4 * b, 4, 127, NC, hM, cM, Bpack, PX4, Wcol4,
                nullptr, nullptr, hD, cD, nullptr);                    // L7
    __syncthreads();
    gemm32_l<0>(2 * b, 2, 63, NC, hD, cD, Bpack, PX4, Wcol4,
                h_out, c_out, nullptr, nullptr, nullptr);              // L6 -> global
}

// ---------------- mega3: levels 5..0 + MLP head, one block x 512 (+prefetch) ----------------
__global__ __launch_bounds__(512) void mega3(
    const float2* __restrict__ NC,
    const ushort* __restrict__ Bpack, const float4* __restrict__ PX4,
    const float4* __restrict__ Wcol4,
    const ushort* __restrict__ h_in, const float* __restrict__ c_in,   // level-6
    const float* __restrict__ W1, const float* __restrict__ b1,
    const float* __restrict__ W2, const float* __restrict__ b2,
    const float* __restrict__ vmask, float* __restrict__ out)
{
    __shared__ __align__(16) ushort hD[64][136];
    __shared__ float cD[32][132];
    __shared__ __align__(16) ushort hM[32][136];
    __shared__ float cM[16][132];
    __shared__ float hs[128];
    __shared__ float as[128];

    const int tid = threadIdx.x;

    prefetch_B(Bpack);
    gemm64_g(0, 32, 31, NC, h_in, c_in, Bpack, PX4, Wcol4, hD, cD);    // L5
    __syncthreads();
    gemm32_l<1>(0, 16, 15, NC, hD, cD, Bpack, PX4, Wcol4,
                nullptr, nullptr, hM, cM, nullptr);                    // L4
    __syncthreads();
    gemm32_l<1>(0, 8, 7, NC, hM, cM, Bpack, PX4, Wcol4,
                nullptr, nullptr, hD, cD, nullptr);                    // L3
    __syncthreads();
    gemm32_l<1>(0, 4, 3, NC, hD, cD, Bpack, PX4, Wcol4,
                nullptr, nullptr, hM, cM, nullptr);                    // L2
    __syncthreads();
    gemm32_l<1>(0, 2, 1, NC, hM, cM, Bpack, PX4, Wcol4,
                nullptr, nullptr, hD, cD, nullptr);                    // L1
    __syncthreads();
    gemm32_l<2>(0, 1, 0, NC, hD, cD, Bpack, PX4, Wcol4,
                nullptr, nullptr, nullptr, nullptr, hs);               // L0 -> hs
    __syncthreads();
    if (tid < 128) {
        float a1h = b1[tid];
        #pragma unroll 4
        for (int k = 0; k < 128; ++k) a1h = fmaf(hs[k], W1[tid * 128 + k], a1h);
        as[tid] = fmaxf(a1h, 0.0f);
    }
    __syncthreads();
    if (tid < 32) {
        float l = b2[tid];
        #pragma unroll 4
        for (int k = 0; k < 128; ++k) l = fmaf(as[k], W2[tid * 128 + k], l);
        l = (l + logf(vmask[tid])) * (1.0f / 3.0f);
        float mx = l;
        #pragma unroll
        for (int o = 16; o >= 1; o >>= 1) mx = fmaxf(mx, __shfl_xor(mx, o, 32));
        const float e = __expf(l - mx);
        float s = e;
        #pragma unroll
        for (int o = 16; o >= 1; o >>= 1) s += __shfl_xor(s, o, 32);
        out[tid] = e / s;
    }
}

extern "C" void kernel_launch(void* const* d_in, const int* in_sizes, int n_in,
                              void* d_out, int out_size, void* d_ws, size_t ws_size,
                              hipStream_t stream)
{
    const int*   node_types = (const int*)  d_in[0];
    const float* node_args  = (const float*)d_in[1];
    const float* vmask      = (const float*)d_in[2];
    const float* emb        = (const float*)d_in[3];
    const float* Wih        = (const float*)d_in[4];
    const float* Whh        = (const float*)d_in[5];
    const float* bih        = (const float*)d_in[6];
    const float* bhh        = (const float*)d_in[7];
    const float* W1         = (const float*)d_in[8];
    const float* b1         = (const float*)d_in[9];
    const float* W2         = (const float*)d_in[10];
    const float* b2         = (const float*)d_in[11];

    char* w = (char*)d_ws;
    ushort* Bpack = (ushort*)(w);                 // 262,144
    float4* PX4   = (float4*)(w + 262144);        // 262,144
    float4* Wcol4 = (float4*)(w + 524288);        // 2,048
    ushort* HLEAF = (ushort*)(w + 526336);        // 32,768
    float*  CLEAF = (float*) (w + 559104);        // 65,536
    float2* NC    = (float2*)(w + 624640);        // 524,288
    ushort* h12   = (ushort*)(w + 1148928);       // 1,048,576
    float*  c12   = (float*) (w + 2197504);       // 1,048,576
    ushort* h6    = (ushort*)(w + 3246080);       // 16,384
    float*  c6    = (float*) (w + 3262464);       // 16,384

    float* out = (float*)d_out;

    prepass<<<384, 256, 0, stream>>>(node_types, node_args, emb,
                                     Wih, Whh, bih, bhh,
                                     Bpack, PX4, Wcol4, HLEAF, CLEAF, NC);
    mega1<<<256, 512, 0, stream>>>(NC, Bpack, PX4, Wcol4, HLEAF, CLEAF, h12, c12);
    mega2<<<32, 512, 0, stream>>>(NC, Bpack, PX4, Wcol4, h12, c12, h6, c6);
    mega3<<<1, 512, 0, stream>>>(NC, Bpack, PX4, Wcol4, h6, c6,
                                 W1, b1, W2, b2, vmask, out);
}

// Round 24
// 131.568 us; speedup vs baseline: 1.0420x; 1.0420x over previous
//
#include <hip/hip_runtime.h>
#include <hip/hip_bf16.h>

typedef __attribute__((ext_vector_type(8))) short s8v;   // 8 x bf16
typedef __attribute__((ext_vector_type(4))) float f32x4; // MFMA acc

__device__ __forceinline__ float sigf(float x) { return 1.0f / (1.0f + __expf(-x)); }
__device__ __forceinline__ float tanh_fast(float x) { return 1.0f - 2.0f / (1.0f + __expf(2.0f * x)); }
__device__ __forceinline__ ushort f2bf(float f) {
    union { __hip_bfloat16 b; ushort u; } v; v.b = __float2bfloat16(f); return v.u;
}

// ---------------- prepass ----------------
// PX4[ty*128+j] = {gi,gf,gg,go}; Wcol4[j]; HLEAF/CLEAF leaf rows; Bpack (Whh, K=256);
// NC[node] = {(float)ty, corr}  (corr = na - emb[ty][127] for ty in {1,2}, else 0).
__global__ __launch_bounds__(256) void prepass(
    const int* __restrict__ nt, const float* __restrict__ na,
    const float* __restrict__ emb,
    const float* __restrict__ Wih, const float* __restrict__ Whh,
    const float* __restrict__ bih, const float* __restrict__ bhh,
    ushort* __restrict__ Bpack, float4* __restrict__ PX4, float4* __restrict__ Wcol4,
    ushort* __restrict__ HLEAF, float* __restrict__ CLEAF, float2* __restrict__ NC)
{
    const int bx = blockIdx.x;
    const int tid = threadIdx.x;
    if (bx < 64) {
        const int gid = bx * 256 + tid;     // (ty, j)
        const int ty = gid >> 7;
        const int j  = gid & 127;
        const float* e = emb + (size_t)ty * 128;
        float d[4];
        #pragma unroll
        for (int g = 0; g < 4; ++g) {
            const int row = g * 256 + j;
            const float* wr = Wih + (size_t)row * 128;
            float acc = bih[row] + bhh[row];
            #pragma unroll 8
            for (int k = 0; k < 128; k += 4) {
                float4 ev = *(const float4*)(e + k);
                float4 wv = *(const float4*)(wr + k);
                acc = fmaf(ev.x, wv.x, acc); acc = fmaf(ev.y, wv.y, acc);
                acc = fmaf(ev.z, wv.z, acc); acc = fmaf(ev.w, wv.w, acc);
            }
            d[g] = acc;
        }
        PX4[gid] = make_float4(d[0], d[1], d[2], d[3]);
        const float cn = sigf(d[0]) * tanh_fast(d[2]);
        CLEAF[gid] = cn;
        HLEAF[gid] = f2bf(sigf(d[3]) * tanh_fast(cn));
        if (ty == 0)
            Wcol4[j] = make_float4(Wih[(size_t)j * 128 + 127],
                                   Wih[(size_t)(256 + j) * 128 + 127],
                                   Wih[(size_t)(512 + j) * 128 + 127],
                                   Wih[(size_t)(768 + j) * 128 + 127]);
    } else if (bx < 128) {
        const int gid = (bx - 64) * 256 + tid;   // Bpack (Whh only, K=256)
        const int nl  = gid & 127;
        const int seg = (gid >> 7) & 3;
        const int rest = gid >> 9;
        const int kk = rest & 7;
        const int bn = rest >> 3;
        const int g  = (nl >> 4) & 3;
        const int j  = bn * 32 + ((nl >> 6) << 4) + (nl & 15);
        const int row = g * 256 + j;
        const int k = kk * 32 + seg * 8;
        const float* src = Whh + (size_t)row * 256 + k;
        float4 w0 = *(const float4*)(src);
        float4 w1 = *(const float4*)(src + 4);
        ushort o[8] = { f2bf(w0.x), f2bf(w0.y), f2bf(w0.z), f2bf(w0.w),
                        f2bf(w1.x), f2bf(w1.y), f2bf(w1.z), f2bf(w1.w) };
        *(s8v*)(Bpack + (size_t)gid * 8) = *(const s8v*)o;
    } else {
        const int node = (bx - 128) * 256 + tid;
        if (node < 65535) {
            const int ty = nt[node];
            float corr = 0.0f;
            if (ty == 1) corr = na[node] - emb[255];
            else if (ty == 2) corr = na[node] - emb[383];
            NC[node] = make_float2((float)ty, corr);
        }
    }
}

// ================= 8-wave helpers (R21-proven pressure, NC epilogue) =================
// M=64, children h/c from GLOBAL -> LDS hO/cO.
__device__ __forceinline__ void gemm64_g(
    int rowbase, int nRows, int startL,
    const float2* __restrict__ NC,
    const ushort* __restrict__ h_in, const float* __restrict__ c_in,
    const ushort* __restrict__ Bpack, const float4* __restrict__ PX4,
    const float4* __restrict__ Wcol4,
    ushort (*hO)[136], float (*cO)[132])
{
    const int tid  = threadIdx.x;
    const int lane = tid & 63;
    const int wave = tid >> 6;
    const int wm2 = wave >> 2;
    const int bn  = wave & 3;
    const int lc = lane & 15, seg = lane >> 4;
    const int koff = seg * 8;

    const ushort* ph[2][2];
    #pragma unroll
    for (int mi = 0; mi < 2; ++mi) {
        int mloc = wm2 * 32 + mi * 16 + lc;
        int dg = rowbase + mloc;
        int dgc = dg < nRows ? dg : nRows - 1;
        ph[mi][0] = h_in + (size_t)(2 * dgc) * 128 + koff;
        ph[mi][1] = h_in + (size_t)(2 * dgc + 1) * 128 + koff;
    }
    const ushort* pb = Bpack + (size_t)bn * 32768 + (size_t)seg * 1024
                             + (size_t)lc * 8;

    f32x4 acc[2][8];
    #pragma unroll
    for (int mi = 0; mi < 2; ++mi)
        #pragma unroll
        for (int f = 0; f < 8; ++f) acc[mi][f] = (f32x4){0.f, 0.f, 0.f, 0.f};

    #pragma unroll
    for (int kk = 0; kk < 8; ++kk) {
        const int hi = kk >> 2, off = (kk & 3) * 32;
        s8v a0 = *(const s8v*)(ph[0][hi] + off);
        s8v a1 = *(const s8v*)(ph[1][hi] + off);
        #pragma unroll
        for (int f = 0; f < 8; ++f) {
            s8v bb = *(const s8v*)(pb + (size_t)kk * 4096 + f * 128);
            acc[0][f] = __builtin_amdgcn_mfma_f32_16x16x32_bf16(a0, bb, acc[0][f], 0, 0, 0);
            acc[1][f] = __builtin_amdgcn_mfma_f32_16x16x32_bf16(a1, bb, acc[1][f], 0, 0, 0);
        }
    }
    #pragma unroll
    for (int bh = 0; bh < 2; ++bh) {
        const int j = bn * 32 + bh * 16 + lc;
        const float4 wc = Wcol4[j];
        #pragma unroll
        for (int mi = 0; mi < 2; ++mi) {
            #pragma unroll
            for (int r = 0; r < 4; ++r) {
                const int mloc = wm2 * 32 + mi * 16 + seg * 4 + r;
                const int dg = rowbase + mloc;
                if (dg < nRows) {
                    const float2 nc = NC[startL + dg];
                    const int ty = (int)nc.x;
                    const float corr = nc.y;
                    const float4 px = PX4[(size_t)ty * 128 + j];
                    const float gi = acc[mi][bh * 4 + 0][r] + px.x + corr * wc.x;
                    const float gf = acc[mi][bh * 4 + 1][r] + px.y + corr * wc.y;
                    const float gg = acc[mi][bh * 4 + 2][r] + px.z + corr * wc.z;
                    const float go = acc[mi][bh * 4 + 3][r] + px.w + corr * wc.w;
                    const float c0 = c_in[(size_t)dg * 128 + j];
                    const float cn = sigf(gf) * c0 + sigf(gi) * tanh_fast(gg);
                    const float hn = sigf(go) * tanh_fast(cn);
                    hO[mloc][j] = f2bf(hn);
                    if (!(mloc & 1)) cO[mloc >> 1][j] = cn;
                }
            }
        }
    }
}

// M=64, children from LDS (hIn 128 rows) -> LDS hO/cO. Exactly 64 rows.
__device__ __forceinline__ void gemm64_l(
    int startL, int gbase,
    const float2* __restrict__ NC,
    const ushort (*hIn)[136], const float (*cIn)[132],
    const ushort* __restrict__ Bpack, const float4* __restrict__ PX4,
    const float4* __restrict__ Wcol4,
    ushort (*hO)[136], float (*cO)[132])
{
    const int tid  = threadIdx.x;
    const int lane = tid & 63;
    const int wave = tid >> 6;
    const int wm2 = wave >> 2;
    const int bn  = wave & 3;
    const int lc = lane & 15, seg = lane >> 4;
    const int koff = seg * 8;

    const int m0 = wm2 * 32 + lc;
    const int m1 = m0 + 16;
    const ushort* pb = Bpack + (size_t)bn * 32768 + (size_t)seg * 1024
                             + (size_t)lc * 8;

    f32x4 acc[2][8];
    #pragma unroll
    for (int mi = 0; mi < 2; ++mi)
        #pragma unroll
        for (int f = 0; f < 8; ++f) acc[mi][f] = (f32x4){0.f, 0.f, 0.f, 0.f};

    #pragma unroll
    for (int kk = 0; kk < 8; ++kk) {
        const int hi = kk >> 2, off = (kk & 3) * 32;
        s8v a0 = *(const s8v*)(&hIn[2 * m0 + hi][off + koff]);
        s8v a1 = *(const s8v*)(&hIn[2 * m1 + hi][off + koff]);
        #pragma unroll
        for (int f = 0; f < 8; ++f) {
            s8v bb = *(const s8v*)(pb + (size_t)kk * 4096 + f * 128);
            acc[0][f] = __builtin_amdgcn_mfma_f32_16x16x32_bf16(a0, bb, acc[0][f], 0, 0, 0);
            acc[1][f] = __builtin_amdgcn_mfma_f32_16x16x32_bf16(a1, bb, acc[1][f], 0, 0, 0);
        }
    }
    #pragma unroll
    for (int bh = 0; bh < 2; ++bh) {
        const int j = bn * 32 + bh * 16 + lc;
        const float4 wc = Wcol4[j];
        #pragma unroll
        for (int mi = 0; mi < 2; ++mi) {
            #pragma unroll
            for (int r = 0; r < 4; ++r) {
                const int mloc = wm2 * 32 + mi * 16 + seg * 4 + r;
                const float2 nc = NC[startL + gbase + mloc];
                const int ty = (int)nc.x;
                const float corr = nc.y;
                const float4 px = PX4[(size_t)ty * 128 + j];
                const float gi = acc[mi][bh * 4 + 0][r] + px.x + corr * wc.x;
                const float gf = acc[mi][bh * 4 + 1][r] + px.y + corr * wc.y;
                const float gg = acc[mi][bh * 4 + 2][r] + px.z + corr * wc.z;
                const float go = acc[mi][bh * 4 + 3][r] + px.w + corr * wc.w;
                const float c0 = cIn[mloc][j];
                const float cn = sigf(gf) * c0 + sigf(gi) * tanh_fast(gg);
                const float hn = sigf(go) * tanh_fast(cn);
                hO[mloc][j] = f2bf(hn);
                if (!(mloc & 1)) cO[mloc >> 1][j] = cn;
            }
        }
    }
}

// M<=32, children from LDS. OUT: 0=global, 1=LDS, 2=root hs.
template<int OUT>
__device__ __forceinline__ void gemm32_l(
    int gbase, int nloc, int startL,
    const float2* __restrict__ NC,
    const ushort (*hIn)[136], const float (*cIn)[132],
    const ushort* __restrict__ Bpack, const float4* __restrict__ PX4,
    const float4* __restrict__ Wcol4,
    ushort* __restrict__ h_out, float* __restrict__ c_out,
    ushort (*hOL)[136], float (*cOL)[132], float* hs)
{
    const int tid  = threadIdx.x;
    const int lane = tid & 63;
    const int wave = tid >> 6;
    const int bn = wave >> 1, wn = wave & 1;
    const int lc = lane & 15, seg = lane >> 4;
    const int koff = seg * 8;

    int mcl[2];
    #pragma unroll
    for (int mi = 0; mi < 2; ++mi) {
        int m = mi * 16 + lc;
        mcl[mi] = m < nloc ? m : nloc - 1;
    }
    const ushort* pb = Bpack + (size_t)bn * 32768 + (size_t)seg * 1024
                             + (size_t)(wn * 64 + lc) * 8;

    f32x4 acc[2][4];
    #pragma unroll
    for (int mi = 0; mi < 2; ++mi)
        #pragma unroll
        for (int f = 0; f < 4; ++f) acc[mi][f] = (f32x4){0.f, 0.f, 0.f, 0.f};

    #pragma unroll
    for (int kk = 0; kk < 8; ++kk) {
        const int hi = kk >> 2, off = (kk & 3) * 32;
        s8v a0 = *(const s8v*)(&hIn[2 * mcl[0] + hi][off + koff]);
        s8v a1 = *(const s8v*)(&hIn[2 * mcl[1] + hi][off + koff]);
        #pragma unroll
        for (int f = 0; f < 4; ++f) {
            s8v bb = *(const s8v*)(pb + (size_t)kk * 4096 + f * 128);
            acc[0][f] = __builtin_amdgcn_mfma_f32_16x16x32_bf16(a0, bb, acc[0][f], 0, 0, 0);
            acc[1][f] = __builtin_amdgcn_mfma_f32_16x16x32_bf16(a1, bb, acc[1][f], 0, 0, 0);
        }
    }

    const int j = bn * 32 + wn * 16 + lc;
    const float4 wc = Wcol4[j];
    #pragma unroll
    for (int mi = 0; mi < 2; ++mi) {
        #pragma unroll
        for (int r = 0; r < 4; ++r) {
            const int m = mi * 16 + seg * 4 + r;
            if (m < nloc) {
                const int mPg = gbase + m;
                const float2 nc = NC[startL + mPg];
                const int ty = (int)nc.x;
                const float corr = nc.y;
                const float4 px = PX4[(size_t)ty * 128 + j];
                const float gi = acc[mi][0][r] + px.x + corr * wc.x;
                const float gf = acc[mi][1][r] + px.y + corr * wc.y;
                const float gg = acc[mi][2][r] + px.z + corr * wc.z;
                const float go = acc[mi][3][r] + px.w + corr * wc.w;
                const float c0 = cIn[m][j];
                const float cn = sigf(gf) * c0 + sigf(gi) * tanh_fast(gg);
                const float hn = sigf(go) * tanh_fast(cn);
                if (OUT == 0) {
                    h_out[(size_t)mPg * 128 + j] = f2bf(hn);
                    if (!(mPg & 1)) c_out[(size_t)(mPg >> 1) * 128 + j] = cn;
                } else if (OUT == 1) {
                    hOL[m][j] = f2bf(hn);
                    if (!(m & 1)) cOL[m >> 1][j] = cn;
                } else {
                    hs[j] = hn;
                }
            }
        }
    }
}

// ---------------- mega1: levels 15..12, 256 blocks x 512 (128 leaves/block) ----------------
__global__ __launch_bounds__(512) void mega1(
    const float2* __restrict__ NC,
    const ushort* __restrict__ Bpack, const float4* __restrict__ PX4,
    const float4* __restrict__ Wcol4,
    const ushort* __restrict__ HLEAF, const float* __restrict__ CLEAF,
    ushort* __restrict__ h_out, float* __restrict__ c_out)   // level-12
{
    __shared__ __align__(16) ushort hD[128][136];
    __shared__ float cD[64][132];
    __shared__ __align__(16) ushort hM[64][136];
    __shared__ float cM[32][132];

    const int tid = threadIdx.x;
    const int b = blockIdx.x;

    // stage 0: 128 leaves via HLEAF/CLEAF row copies
    {
        const int mloc = tid >> 2;   // 0..127
        const int p4   = tid & 3;    // 32-elem chunk
        const int node = 32767 + 128 * b + mloc;
        const float2 nc = NC[node];
        const int ty = (int)nc.x;
        if (ty != 1 && ty != 2) {
            #pragma unroll
            for (int q = 0; q < 4; ++q)
                *(s8v*)(&hD[mloc][p4 * 32 + q * 8]) =
                    *(const s8v*)(HLEAF + (size_t)ty * 128 + p4 * 32 + q * 8);
            if (!(mloc & 1)) {
                const float4* cr = (const float4*)(CLEAF + (size_t)ty * 128 + p4 * 32);
                float4* cw = (float4*)(&cD[mloc >> 1][p4 * 32]);
                #pragma unroll
                for (int q = 0; q < 8; ++q) cw[q] = cr[q];
            }
        } else {
            const float corr = nc.y;
            #pragma unroll
            for (int q = 0; q < 32; ++q) {
                const int jj = p4 * 32 + q;
                const float4 px = PX4[(size_t)ty * 128 + jj];
                const float4 wc = Wcol4[jj];
                const float gi = px.x + corr * wc.x;
                const float gg = px.z + corr * wc.z;
                const float go = px.w + corr * wc.w;
                const float cn = sigf(gi) * tanh_fast(gg);
                const float hn = sigf(go) * tanh_fast(cn);
                hD[mloc][jj] = f2bf(hn);
                if (!(mloc & 1)) cD[mloc >> 1][jj] = cn;
            }
        }
    }
    __syncthreads();
    gemm64_l(16383, 64 * b, NC, hD, cD, Bpack, PX4, Wcol4, hM, cM);   // L14
    __syncthreads();
    gemm32_l<1>(32 * b, 32, 8191, NC, hM, cM, Bpack, PX4, Wcol4,
                nullptr, nullptr, hD, cD, nullptr);                    // L13
    __syncthreads();
    gemm32_l<0>(16 * b, 16, 4095, NC, hD, cD, Bpack, PX4, Wcol4,
                h_out, c_out, nullptr, nullptr, nullptr);              // L12 -> global
}

// ---------------- mega2: levels 11..6, 32 blocks x 512 ----------------
__global__ __launch_bounds__(512) void mega2(
    const float2* __restrict__ NC,
    const ushort* __restrict__ Bpack, const float4* __restrict__ PX4,
    const float4* __restrict__ Wcol4,
    const ushort* __restrict__ h_in, const float* __restrict__ c_in,   // level-12
    ushort* __restrict__ h_out, float* __restrict__ c_out)             // level-6
{
    __shared__ __align__(16) ushort hD[64][136];
    __shared__ float cD[32][132];
    __shared__ __align__(16) ushort hM[32][136];
    __shared__ float cM[16][132];

    const int b = blockIdx.x;

    gemm64_g(64 * b, 2048, 2047, NC, h_in, c_in,
             Bpack, PX4, Wcol4, hD, cD);                               // L11
    __syncthreads();
    gemm32_l<1>(32 * b, 32, 1023, NC, hD, cD, Bpack, PX4, Wcol4,
                nullptr, nullptr, hM, cM, nullptr);                    // L10
    __syncthreads();
    gemm32_l<1>(16 * b, 16, 511, NC, hM, cM, Bpack, PX4, Wcol4,
                nullptr, nullptr, hD, cD, nullptr);                    // L9
    __syncthreads();
    gemm32_l<1>(8 * b, 8, 255, NC, hD, cD, Bpack, PX4, Wcol4,
                nullptr, nullptr, hM, cM, nullptr);                    // L8
    __syncthreads();
    gemm32_l<1>(4 * b, 4, 127, NC, hM, cM, Bpack, PX4, Wcol4,
                nullptr, nullptr, hD, cD, nullptr);                    // L7
    __syncthreads();
    gemm32_l<0>(2 * b, 2, 63, NC, hD, cD, Bpack, PX4, Wcol4,
                h_out, c_out, nullptr, nullptr, nullptr);              // L6 -> global
}

// ---------------- mega3: levels 5..0 + MLP head, one block x 512 ----------------
__global__ __launch_bounds__(512) void mega3(
    const float2* __restrict__ NC,
    const ushort* __restrict__ Bpack, const float4* __restrict__ PX4,
    const float4* __restrict__ Wcol4,
    const ushort* __restrict__ h_in, const float* __restrict__ c_in,   // level-6
    const float* __restrict__ W1, const float* __restrict__ b1,
    const float* __restrict__ W2, const float* __restrict__ b2,
    const float* __restrict__ vmask, float* __restrict__ out)
{
    __shared__ __align__(16) ushort hD[64][136];
    __shared__ float cD[32][132];
    __shared__ __align__(16) ushort hM[32][136];
    __shared__ float cM[16][132];
    __shared__ float hs[128];
    __shared__ float as[128];

    const int tid = threadIdx.x;

    gemm64_g(0, 32, 31, NC, h_in, c_in, Bpack, PX4, Wcol4, hD, cD);    // L5
    __syncthreads();
    gemm32_l<1>(0, 16, 15, NC, hD, cD, Bpack, PX4, Wcol4,
                nullptr, nullptr, hM, cM, nullptr);                    // L4
    __syncthreads();
    gemm32_l<1>(0, 8, 7, NC, hM, cM, Bpack, PX4, Wcol4,
                nullptr, nullptr, hD, cD, nullptr);                    // L3
    __syncthreads();
    gemm32_l<1>(0, 4, 3, NC, hD, cD, Bpack, PX4, Wcol4,
                nullptr, nullptr, hM, cM, nullptr);                    // L2
    __syncthreads();
    gemm32_l<1>(0, 2, 1, NC, hM, cM, Bpack, PX4, Wcol4,
                nullptr, nullptr, hD, cD, nullptr);                    // L1
    __syncthreads();
    gemm32_l<2>(0, 1, 0, NC, hD, cD, Bpack, PX4, Wcol4,
                nullptr, nullptr, nullptr, nullptr, hs);               // L0 -> hs
    __syncthreads();
    if (tid < 128) {
        float a1h = b1[tid];
        #pragma unroll 4
        for (int k = 0; k < 128; ++k) a1h = fmaf(hs[k], W1[tid * 128 + k], a1h);
        as[tid] = fmaxf(a1h, 0.0f);
    }
    __syncthreads();
    if (tid < 32) {
        float l = b2[tid];
        #pragma unroll 4
        for (int k = 0; k < 128; ++k) l = fmaf(as[k], W2[tid * 128 + k], l);
        l = (l + logf(vmask[tid])) * (1.0f / 3.0f);
        float mx = l;
        #pragma unroll
        for (int o = 16; o >= 1; o >>= 1) mx = fmaxf(mx, __shfl_xor(mx, o, 32));
        const float e = __expf(l - mx);
        float s = e;
        #pragma unroll
        for (int o = 16; o >= 1; o >>= 1) s += __shfl_xor(s, o, 32);
        out[tid] = e / s;
    }
}

extern "C" void kernel_launch(void* const* d_in, const int* in_sizes, int n_in,
                              void* d_out, int out_size, void* d_ws, size_t ws_size,
                              hipStream_t stream)
{
    const int*   node_types = (const int*)  d_in[0];
    const float* node_args  = (const float*)d_in[1];
    const float* vmask      = (const float*)d_in[2];
    const float* emb        = (const float*)d_in[3];
    const float* Wih        = (const float*)d_in[4];
    const float* Whh        = (const float*)d_in[5];
    const float* bih        = (const float*)d_in[6];
    const float* bhh        = (const float*)d_in[7];
    const float* W1         = (const float*)d_in[8];
    const float* b1         = (const float*)d_in[9];
    const float* W2         = (const float*)d_in[10];
    const float* b2         = (const float*)d_in[11];

    char* w = (char*)d_ws;
    ushort* Bpack = (ushort*)(w);                 // 262,144
    float4* PX4   = (float4*)(w + 262144);        // 262,144
    float4* Wcol4 = (float4*)(w + 524288);        // 2,048
    ushort* HLEAF = (ushort*)(w + 526336);        // 32,768
    float*  CLEAF = (float*) (w + 559104);        // 65,536
    float2* NC    = (float2*)(w + 624640);        // 65536*8 = 524,288
    ushort* h12   = (ushort*)(w + 1148928);       // 4096*128*2 = 1,048,576
    float*  c12   = (float*) (w + 2197504);       // 2048*128*4 = 1,048,576
    ushort* h6    = (ushort*)(w + 3246080);       // 64*128*2 = 16,384
    float*  c6    = (float*) (w + 3262464);       // 32*128*4 = 16,384

    float* out = (float*)d_out;

    prepass<<<384, 256, 0, stream>>>(node_types, node_args, emb,
                                     Wih, Whh, bih, bhh,
                                     Bpack, PX4, Wcol4, HLEAF, CLEAF, NC);
    mega1<<<256, 512, 0, stream>>>(NC, Bpack, PX4, Wcol4, HLEAF, CLEAF, h12, c12);
    mega2<<<32, 512, 0, stream>>>(NC, Bpack, PX4, Wcol4, h12, c12, h6, c6);
    mega3<<<1, 512, 0, stream>>>(NC, Bpack, PX4, Wcol4, h6, c6,
                                 W1, b1, W2, b2, vmask, out);
}

// Round 25
// 128.467 us; speedup vs baseline: 1.0672x; 1.0241x over previous
//
#include <hip/hip_runtime.h>
#include <hip/hip_bf16.h>

typedef __attribute__((ext_vector_type(8))) short s8v;   // 8 x bf16
typedef __attribute__((ext_vector_type(4))) float f32x4; // MFMA acc

__device__ __forceinline__ float sigf(float x) { return 1.0f / (1.0f + __expf(-x)); }
__device__ __forceinline__ float tanh_fast(float x) { return 1.0f - 2.0f / (1.0f + __expf(2.0f * x)); }
__device__ __forceinline__ ushort f2bf(float f) {
    union { __hip_bfloat16 b; ushort u; } v; v.b = __float2bfloat16(f); return v.u;
}
__device__ __forceinline__ float bf2f(ushort u) {
    union { float f; unsigned int i; } v; v.i = ((unsigned int)u) << 16; return v.f;
}

// ---------------- prepass (R22-proven) ----------------
__global__ __launch_bounds__(256) void prepass(
    const int* __restrict__ nt, const float* __restrict__ na,
    const float* __restrict__ emb,
    const float* __restrict__ Wih, const float* __restrict__ Whh,
    const float* __restrict__ bih, const float* __restrict__ bhh,
    ushort* __restrict__ Bpack, float4* __restrict__ PX4, float4* __restrict__ Wcol4,
    ushort* __restrict__ HLEAF, float* __restrict__ CLEAF, float2* __restrict__ NC)
{
    const int bx = blockIdx.x;
    const int tid = threadIdx.x;
    if (bx < 64) {
        const int gid = bx * 256 + tid;     // (ty, j)
        const int ty = gid >> 7;
        const int j  = gid & 127;
        const float* e = emb + (size_t)ty * 128;
        float d[4];
        #pragma unroll
        for (int g = 0; g < 4; ++g) {
            const int row = g * 256 + j;
            const float* wr = Wih + (size_t)row * 128;
            float acc = bih[row] + bhh[row];
            #pragma unroll 8
            for (int k = 0; k < 128; k += 4) {
                float4 ev = *(const float4*)(e + k);
                float4 wv = *(const float4*)(wr + k);
                acc = fmaf(ev.x, wv.x, acc); acc = fmaf(ev.y, wv.y, acc);
                acc = fmaf(ev.z, wv.z, acc); acc = fmaf(ev.w, wv.w, acc);
            }
            d[g] = acc;
        }
        PX4[gid] = make_float4(d[0], d[1], d[2], d[3]);
        const float cn = sigf(d[0]) * tanh_fast(d[2]);
        CLEAF[gid] = cn;
        HLEAF[gid] = f2bf(sigf(d[3]) * tanh_fast(cn));
        if (ty == 0)
            Wcol4[j] = make_float4(Wih[(size_t)j * 128 + 127],
                                   Wih[(size_t)(256 + j) * 128 + 127],
                                   Wih[(size_t)(512 + j) * 128 + 127],
                                   Wih[(size_t)(768 + j) * 128 + 127]);
    } else if (bx < 128) {
        const int gid = (bx - 64) * 256 + tid;   // Bpack (Whh only, K=256)
        const int nl  = gid & 127;
        const int seg = (gid >> 7) & 3;
        const int rest = gid >> 9;
        const int kk = rest & 7;
        const int bn = rest >> 3;
        const int g  = (nl >> 4) & 3;
        const int j  = bn * 32 + ((nl >> 6) << 4) + (nl & 15);
        const int row = g * 256 + j;
        const int k = kk * 32 + seg * 8;
        const float* src = Whh + (size_t)row * 256 + k;
        float4 w0 = *(const float4*)(src);
        float4 w1 = *(const float4*)(src + 4);
        ushort o[8] = { f2bf(w0.x), f2bf(w0.y), f2bf(w0.z), f2bf(w0.w),
                        f2bf(w1.x), f2bf(w1.y), f2bf(w1.z), f2bf(w1.w) };
        *(s8v*)(Bpack + (size_t)gid * 8) = *(const s8v*)o;
    } else {
        const int node = (bx - 128) * 256 + tid;
        if (node < 65535) {
            const int ty = nt[node];
            float corr = 0.0f;
            if (ty == 1) corr = na[node] - emb[255];
            else if (ty == 2) corr = na[node] - emb[383];
            NC[node] = make_float2((float)ty, corr);
        }
    }
}

// ================= helpers (R22-identical math) =================
__device__ __forceinline__ void gemm64_g(
    int rowbase, int nRows, int startL,
    const float2* __restrict__ NC,
    const ushort* __restrict__ h_in, const float* __restrict__ c_in,
    const ushort* __restrict__ Bpack, const float4* __restrict__ PX4,
    const float4* __restrict__ Wcol4,
    ushort (*hO)[136], float (*cO)[132])
{
    const int tid  = threadIdx.x;
    const int lane = tid & 63;
    const int wave = tid >> 6;
    const int wm2 = wave >> 2;
    const int bn  = wave & 3;
    const int lc = lane & 15, seg = lane >> 4;
    const int koff = seg * 8;

    const ushort* ph[2][2];
    #pragma unroll
    for (int mi = 0; mi < 2; ++mi) {
        int mloc = wm2 * 32 + mi * 16 + lc;
        int dg = rowbase + mloc;
        int dgc = dg < nRows ? dg : nRows - 1;
        ph[mi][0] = h_in + (size_t)(2 * dgc) * 128 + koff;
        ph[mi][1] = h_in + (size_t)(2 * dgc + 1) * 128 + koff;
    }
    const ushort* pb = Bpack + (size_t)bn * 32768 + (size_t)seg * 1024
                             + (size_t)lc * 8;

    f32x4 acc[2][8];
    #pragma unroll
    for (int mi = 0; mi < 2; ++mi)
        #pragma unroll
        for (int f = 0; f < 8; ++f) acc[mi][f] = (f32x4){0.f, 0.f, 0.f, 0.f};

    #pragma unroll
    for (int kk = 0; kk < 8; ++kk) {
        const int hi = kk >> 2, off = (kk & 3) * 32;
        s8v a0 = *(const s8v*)(ph[0][hi] + off);
        s8v a1 = *(const s8v*)(ph[1][hi] + off);
        #pragma unroll
        for (int f = 0; f < 8; ++f) {
            s8v bb = *(const s8v*)(pb + (size_t)kk * 4096 + f * 128);
            acc[0][f] = __builtin_amdgcn_mfma_f32_16x16x32_bf16(a0, bb, acc[0][f], 0, 0, 0);
            acc[1][f] = __builtin_amdgcn_mfma_f32_16x16x32_bf16(a1, bb, acc[1][f], 0, 0, 0);
        }
    }
    #pragma unroll
    for (int bh = 0; bh < 2; ++bh) {
        const int j = bn * 32 + bh * 16 + lc;
        const float4 wc = Wcol4[j];
        #pragma unroll
        for (int mi = 0; mi < 2; ++mi) {
            #pragma unroll
            for (int r = 0; r < 4; ++r) {
                const int mloc = wm2 * 32 + mi * 16 + seg * 4 + r;
                const int dg = rowbase + mloc;
                if (dg < nRows) {
                    const float2 nc = NC[startL + dg];
                    const int ty = (int)nc.x;
                    const float corr = nc.y;
                    const float4 px = PX4[(size_t)ty * 128 + j];
                    const float gi = acc[mi][bh * 4 + 0][r] + px.x + corr * wc.x;
                    const float gf = acc[mi][bh * 4 + 1][r] + px.y + corr * wc.y;
                    const float gg = acc[mi][bh * 4 + 2][r] + px.z + corr * wc.z;
                    const float go = acc[mi][bh * 4 + 3][r] + px.w + corr * wc.w;
                    const float c0 = c_in[(size_t)dg * 128 + j];
                    const float cn = sigf(gf) * c0 + sigf(gi) * tanh_fast(gg);
                    const float hn = sigf(go) * tanh_fast(cn);
                    hO[mloc][j] = f2bf(hn);
                    if (!(mloc & 1)) cO[mloc >> 1][j] = cn;
                }
            }
        }
    }
}

__device__ __forceinline__ void gemm64_l(
    int startL, int gbase,
    const float2* __restrict__ NC,
    const ushort (*hIn)[136], const float (*cIn)[132],
    const ushort* __restrict__ Bpack, const float4* __restrict__ PX4,
    const float4* __restrict__ Wcol4,
    ushort (*hO)[136], float (*cO)[132])
{
    const int tid  = threadIdx.x;
    const int lane = tid & 63;
    const int wave = tid >> 6;
    const int wm2 = wave >> 2;
    const int bn  = wave & 3;
    const int lc = lane & 15, seg = lane >> 4;
    const int koff = seg * 8;

    const int m0 = wm2 * 32 + lc;
    const int m1 = m0 + 16;
    const ushort* pb = Bpack + (size_t)bn * 32768 + (size_t)seg * 1024
                             + (size_t)lc * 8;

    f32x4 acc[2][8];
    #pragma unroll
    for (int mi = 0; mi < 2; ++mi)
        #pragma unroll
        for (int f = 0; f < 8; ++f) acc[mi][f] = (f32x4){0.f, 0.f, 0.f, 0.f};

    #pragma unroll
    for (int kk = 0; kk < 8; ++kk) {
        const int hi = kk >> 2, off = (kk & 3) * 32;
        s8v a0 = *(const s8v*)(&hIn[2 * m0 + hi][off + koff]);
        s8v a1 = *(const s8v*)(&hIn[2 * m1 + hi][off + koff]);
        #pragma unroll
        for (int f = 0; f < 8; ++f) {
            s8v bb = *(const s8v*)(pb + (size_t)kk * 4096 + f * 128);
            acc[0][f] = __builtin_amdgcn_mfma_f32_16x16x32_bf16(a0, bb, acc[0][f], 0, 0, 0);
            acc[1][f] = __builtin_amdgcn_mfma_f32_16x16x32_bf16(a1, bb, acc[1][f], 0, 0, 0);
        }
    }
    #pragma unroll
    for (int bh = 0; bh < 2; ++bh) {
        const int j = bn * 32 + bh * 16 + lc;
        const float4 wc = Wcol4[j];
        #pragma unroll
        for (int mi = 0; mi < 2; ++mi) {
            #pragma unroll
            for (int r = 0; r < 4; ++r) {
                const int mloc = wm2 * 32 + mi * 16 + seg * 4 + r;
                const float2 nc = NC[startL + gbase + mloc];
                const int ty = (int)nc.x;
                const float corr = nc.y;
                const float4 px = PX4[(size_t)ty * 128 + j];
                const float gi = acc[mi][bh * 4 + 0][r] + px.x + corr * wc.x;
                const float gf = acc[mi][bh * 4 + 1][r] + px.y + corr * wc.y;
                const float gg = acc[mi][bh * 4 + 2][r] + px.z + corr * wc.z;
                const float go = acc[mi][bh * 4 + 3][r] + px.w + corr * wc.w;
                const float c0 = cIn[mloc][j];
                const float cn = sigf(gf) * c0 + sigf(gi) * tanh_fast(gg);
                const float hn = sigf(go) * tanh_fast(cn);
                hO[mloc][j] = f2bf(hn);
                if (!(mloc & 1)) cO[mloc >> 1][j] = cn;
            }
        }
    }
}

template<int OUT>   // 0=global, 1=LDS
__device__ __forceinline__ void gemm32_l(
    int gbase, int nloc, int startL,
    const float2* __restrict__ NC,
    const ushort (*hIn)[136], const float (*cIn)[132],
    const ushort* __restrict__ Bpack, const float4* __restrict__ PX4,
    const float4* __restrict__ Wcol4,
    ushort* __restrict__ h_out, float* __restrict__ c_out,
    ushort (*hOL)[136], float (*cOL)[132])
{
    const int tid  = threadIdx.x;
    const int lane = tid & 63;
    const int wave = tid >> 6;
    const int bn = wave >> 1, wn = wave & 1;
    const int lc = lane & 15, seg = lane >> 4;
    const int koff = seg * 8;

    int mcl[2];
    #pragma unroll
    for (int mi = 0; mi < 2; ++mi) {
        int m = mi * 16 + lc;
        mcl[mi] = m < nloc ? m : nloc - 1;
    }
    const ushort* pb = Bpack + (size_t)bn * 32768 + (size_t)seg * 1024
                             + (size_t)(wn * 64 + lc) * 8;

    f32x4 acc[2][4];
    #pragma unroll
    for (int mi = 0; mi < 2; ++mi)
        #pragma unroll
        for (int f = 0; f < 4; ++f) acc[mi][f] = (f32x4){0.f, 0.f, 0.f, 0.f};

    #pragma unroll
    for (int kk = 0; kk < 8; ++kk) {
        const int hi = kk >> 2, off = (kk & 3) * 32;
        s8v a0 = *(const s8v*)(&hIn[2 * mcl[0] + hi][off + koff]);
        s8v a1 = *(const s8v*)(&hIn[2 * mcl[1] + hi][off + koff]);
        #pragma unroll
        for (int f = 0; f < 4; ++f) {
            s8v bb = *(const s8v*)(pb + (size_t)kk * 4096 + f * 128);
            acc[0][f] = __builtin_amdgcn_mfma_f32_16x16x32_bf16(a0, bb, acc[0][f], 0, 0, 0);
            acc[1][f] = __builtin_amdgcn_mfma_f32_16x16x32_bf16(a1, bb, acc[1][f], 0, 0, 0);
        }
    }

    const int j = bn * 32 + wn * 16 + lc;
    const float4 wc = Wcol4[j];
    #pragma unroll
    for (int mi = 0; mi < 2; ++mi) {
        #pragma unroll
        for (int r = 0; r < 4; ++r) {
            const int m = mi * 16 + seg * 4 + r;
            if (m < nloc) {
                const int mPg = gbase + m;
                const float2 nc = NC[startL + mPg];
                const int ty = (int)nc.x;
                const float corr = nc.y;
                const float4 px = PX4[(size_t)ty * 128 + j];
                const float gi = acc[mi][0][r] + px.x + corr * wc.x;
                const float gf = acc[mi][1][r] + px.y + corr * wc.y;
                const float gg = acc[mi][2][r] + px.z + corr * wc.z;
                const float go = acc[mi][3][r] + px.w + corr * wc.w;
                const float c0 = cIn[m][j];
                const float cn = sigf(gf) * c0 + sigf(gi) * tanh_fast(gg);
                const float hn = sigf(go) * tanh_fast(cn);
                if (OUT == 0) {
                    h_out[(size_t)mPg * 128 + j] = f2bf(hn);
                    if (!(mPg & 1)) c_out[(size_t)(mPg >> 1) * 128 + j] = cn;
                } else {
                    hOL[m][j] = f2bf(hn);
                    if (!(m & 1)) cOL[m >> 1][j] = cn;
                }
            }
        }
    }
}

// ---------------- mega1: levels 15..12, 256 blocks x 512 ----------------
__global__ __launch_bounds__(512) void mega1(
    const float2* __restrict__ NC,
    const ushort* __restrict__ Bpack, const float4* __restrict__ PX4,
    const float4* __restrict__ Wcol4,
    const ushort* __restrict__ HLEAF, const float* __restrict__ CLEAF,
    ushort* __restrict__ h_out, float* __restrict__ c_out)   // level-12
{
    __shared__ __align__(16) ushort hD[128][136];
    __shared__ float cD[64][132];
    __shared__ __align__(16) ushort hM[64][136];
    __shared__ float cM[32][132];

    const int tid = threadIdx.x;
    const int b = blockIdx.x;

    // stage 0: 128 leaves via HLEAF/CLEAF row copies
    {
        const int mloc = tid >> 2;   // 0..127
        const int p4   = tid & 3;    // 32-elem chunk
        const int node = 32767 + 128 * b + mloc;
        const float2 nc = NC[node];
        const int ty = (int)nc.x;
        if (ty != 1 && ty != 2) {
            #pragma unroll
            for (int q = 0; q < 4; ++q)
                *(s8v*)(&hD[mloc][p4 * 32 + q * 8]) =
                    *(const s8v*)(HLEAF + (size_t)ty * 128 + p4 * 32 + q * 8);
            if (!(mloc & 1)) {
                const float4* cr = (const float4*)(CLEAF + (size_t)ty * 128 + p4 * 32);
                float4* cw = (float4*)(&cD[mloc >> 1][p4 * 32]);
                #pragma unroll
                for (int q = 0; q < 8; ++q) cw[q] = cr[q];
            }
        } else {
            const float corr = nc.y;
            #pragma unroll 1
            for (int q = 0; q < 32; ++q) {
                const int jj = p4 * 32 + q;
                const float4 px = PX4[(size_t)ty * 128 + jj];
                const float4 wc = Wcol4[jj];
                const float gi = px.x + corr * wc.x;
                const float gg = px.z + corr * wc.z;
                const float go = px.w + corr * wc.w;
                const float cn = sigf(gi) * tanh_fast(gg);
                const float hn = sigf(go) * tanh_fast(cn);
                hD[mloc][jj] = f2bf(hn);
                if (!(mloc & 1)) cD[mloc >> 1][jj] = cn;
            }
        }
    }
    __syncthreads();
    gemm64_l(16383, 64 * b, NC, hD, cD, Bpack, PX4, Wcol4, hM, cM);   // L14
    __syncthreads();
    gemm32_l<1>(32 * b, 32, 8191, NC, hM, cM, Bpack, PX4, Wcol4,
                nullptr, nullptr, hD, cD);                             // L13
    __syncthreads();
    gemm32_l<0>(16 * b, 16, 4095, NC, hD, cD, Bpack, PX4, Wcol4,
                h_out, c_out, nullptr, nullptr);                       // L12 -> global
}

// ---------------- mega2: levels 11..6, 32 blocks x 512 (looped stages) ----------------
__global__ __launch_bounds__(512) void mega2(
    const float2* __restrict__ NC,
    const ushort* __restrict__ Bpack, const float4* __restrict__ PX4,
    const float4* __restrict__ Wcol4,
    const ushort* __restrict__ h_in, const float* __restrict__ c_in,   // level-12
    ushort* __restrict__ h_out, float* __restrict__ c_out)             // level-6
{
    __shared__ __align__(16) ushort hD[64][136];
    __shared__ float cD[32][132];
    __shared__ __align__(16) ushort hM[32][136];
    __shared__ float cM[16][132];

    const int b = blockIdx.x;

    gemm64_g(64 * b, 2048, 2047, NC, h_in, c_in,
             Bpack, PX4, Wcol4, hD, cD);                               // L11
    // L10..L7 in a rolled loop (one gemm32_l<1> instance -> small I$ footprint)
    ushort (*hi_)[136] = hD;  float (*ci_)[132] = cD;
    ushort (*ho_)[136] = hM;  float (*co_)[132] = cM;
    #pragma unroll 1
    for (int s = 0; s < 4; ++s) {
        __syncthreads();
        const int n = 32 >> s;                    // 32,16,8,4
        gemm32_l<1>(n * b, n, (1024 >> s) - 1, NC, hi_, ci_, Bpack, PX4, Wcol4,
                    nullptr, nullptr, ho_, co_);
        ushort (*th)[136] = hi_; hi_ = ho_; ho_ = th;
        float  (*tc)[132] = ci_; ci_ = co_; co_ = tc;
    }
    __syncthreads();
    gemm32_l<0>(2 * b, 2, 63, NC, hi_, ci_, Bpack, PX4, Wcol4,
                h_out, c_out, nullptr, nullptr);                       // L6 -> global
}

// ---------------- mega3: levels 5..0 + MLP head, one block x 512 (looped stages) ----------------
__global__ __launch_bounds__(512) void mega3(
    const float2* __restrict__ NC,
    const ushort* __restrict__ Bpack, const float4* __restrict__ PX4,
    const float4* __restrict__ Wcol4,
    const ushort* __restrict__ h_in, const float* __restrict__ c_in,   // level-6
    const float* __restrict__ W1, const float* __restrict__ b1,
    const float* __restrict__ W2, const float* __restrict__ b2,
    const float* __restrict__ vmask, float* __restrict__ out)
{
    __shared__ __align__(16) ushort hD[64][136];
    __shared__ float cD[32][132];
    __shared__ __align__(16) ushort hM[32][136];
    __shared__ float cM[16][132];
    __shared__ float hs[128];
    __shared__ float as[128];

    const int tid = threadIdx.x;

    gemm64_g(0, 32, 31, NC, h_in, c_in, Bpack, PX4, Wcol4, hD, cD);    // L5
    // L4..L0 in a rolled loop
    ushort (*hi_)[136] = hD;  float (*ci_)[132] = cD;
    ushort (*ho_)[136] = hM;  float (*co_)[132] = cM;
    #pragma unroll 1
    for (int s = 0; s < 5; ++s) {
        __syncthreads();
        const int n = 16 >> s;                    // 16,8,4,2,1
        gemm32_l<1>(0, n, n - 1, NC, hi_, ci_, Bpack, PX4, Wcol4,
                    nullptr, nullptr, ho_, co_);
        ushort (*th)[136] = hi_; hi_ = ho_; ho_ = th;
        float  (*tc)[132] = ci_; ci_ = co_; co_ = tc;
    }
    __syncthreads();
    // root h (bf16) is row 0 of hi_
    if (tid < 128) hs[tid] = bf2f(hi_[0][tid]);
    __syncthreads();
    if (tid < 128) {
        float a1h = b1[tid];
        #pragma unroll 4
        for (int k = 0; k < 128; ++k) a1h = fmaf(hs[k], W1[tid * 128 + k], a1h);
        as[tid] = fmaxf(a1h, 0.0f);
    }
    __syncthreads();
    if (tid < 32) {
        float l = b2[tid];
        #pragma unroll 4
        for (int k = 0; k < 128; ++k) l = fmaf(as[k], W2[tid * 128 + k], l);
        l = (l + logf(vmask[tid])) * (1.0f / 3.0f);
        float mx = l;
        #pragma unroll
        for (int o = 16; o >= 1; o >>= 1) mx = fmaxf(mx, __shfl_xor(mx, o, 32));
        const float e = __expf(l - mx);
        float s = e;
        #pragma unroll
        for (int o = 16; o >= 1; o >>= 1) s += __shfl_xor(s, o, 32);
        out[tid] = e / s;
    }
}

extern "C" void kernel_launch(void* const* d_in, const int* in_sizes, int n_in,
                              void* d_out, int out_size, void* d_ws, size_t ws_size,
                              hipStream_t stream)
{
    const int*   node_types = (const int*)  d_in[0];
    const float* node_args  = (const float*)d_in[1];
    const float* vmask      = (const float*)d_in[2];
    const float* emb        = (const float*)d_in[3];
    const float* Wih        = (const float*)d_in[4];
    const float* Whh        = (const float*)d_in[5];
    const float* bih        = (const float*)d_in[6];
    const float* bhh        = (const float*)d_in[7];
    const float* W1         = (const float*)d_in[8];
    const float* b1         = (const float*)d_in[9];
    const float* W2         = (const float*)d_in[10];
    const float* b2         = (const float*)d_in[11];

    char* w = (char*)d_ws;
    ushort* Bpack = (ushort*)(w);                 // 262,144
    float4* PX4   = (float4*)(w + 262144);        // 262,144
    float4* Wcol4 = (float4*)(w + 524288);        // 2,048
    ushort* HLEAF = (ushort*)(w + 526336);        // 32,768
    float*  CLEAF = (float*) (w + 559104);        // 65,536
    float2* NC    = (float2*)(w + 624640);        // 524,288
    ushort* h12   = (ushort*)(w + 1148928);       // 1,048,576
    float*  c12   = (float*) (w + 2197504);       // 1,048,576
    ushort* h6    = (ushort*)(w + 3246080);       // 16,384
    float*  c6    = (float*) (w + 3262464);       // 16,384

    float* out = (float*)d_out;

    prepass<<<384, 256, 0, stream>>>(node_types, node_args, emb,
                                     Wih, Whh, bih, bhh,
                                     Bpack, PX4, Wcol4, HLEAF, CLEAF, NC);
    mega1<<<256, 512, 0, stream>>>(NC, Bpack, PX4, Wcol4, HLEAF, CLEAF, h12, c12);
    mega2<<<32, 512, 0, stream>>>(NC, Bpack, PX4, Wcol4, h12, c12, h6, c6);
    mega3<<<1, 512, 0, stream>>>(NC, Bpack, PX4, Wcol4, h6, c6,
                                 W1, b1, W2, b2, vmask, out);
}

// Round 26
// 123.898 us; speedup vs baseline: 1.1065x; 1.0369x over previous
//
#include <hip/hip_runtime.h>
#include <hip/hip_bf16.h>

typedef __attribute__((ext_vector_type(8))) short s8v;   // 8 x bf16
typedef __attribute__((ext_vector_type(4))) float f32x4; // MFMA acc

__device__ __forceinline__ float sigf(float x) { return 1.0f / (1.0f + __expf(-x)); }
__device__ __forceinline__ float tanh_fast(float x) { return 1.0f - 2.0f / (1.0f + __expf(2.0f * x)); }
__device__ __forceinline__ ushort f2bf(float f) {
    union { __hip_bfloat16 b; ushort u; } v; v.b = __float2bfloat16(f); return v.u;
}
__device__ __forceinline__ float bf2f(ushort u) {
    union { float f; unsigned int i; } v; v.i = ((unsigned int)u) << 16; return v.f;
}

// ---------------- prepass (R22-proven) ----------------
__global__ __launch_bounds__(256) void prepass(
    const int* __restrict__ nt, const float* __restrict__ na,
    const float* __restrict__ emb,
    const float* __restrict__ Wih, const float* __restrict__ Whh,
    const float* __restrict__ bih, const float* __restrict__ bhh,
    ushort* __restrict__ Bpack, float4* __restrict__ PX4, float4* __restrict__ Wcol4,
    ushort* __restrict__ HLEAF, float* __restrict__ CLEAF, float2* __restrict__ NC)
{
    const int bx = blockIdx.x;
    const int tid = threadIdx.x;
    if (bx < 64) {
        const int gid = bx * 256 + tid;     // (ty, j)
        const int ty = gid >> 7;
        const int j  = gid & 127;
        const float* e = emb + (size_t)ty * 128;
        float d[4];
        #pragma unroll
        for (int g = 0; g < 4; ++g) {
            const int row = g * 256 + j;
            const float* wr = Wih + (size_t)row * 128;
            float acc = bih[row] + bhh[row];
            #pragma unroll 8
            for (int k = 0; k < 128; k += 4) {
                float4 ev = *(const float4*)(e + k);
                float4 wv = *(const float4*)(wr + k);
                acc = fmaf(ev.x, wv.x, acc); acc = fmaf(ev.y, wv.y, acc);
                acc = fmaf(ev.z, wv.z, acc); acc = fmaf(ev.w, wv.w, acc);
            }
            d[g] = acc;
        }
        PX4[gid] = make_float4(d[0], d[1], d[2], d[3]);
        const float cn = sigf(d[0]) * tanh_fast(d[2]);
        CLEAF[gid] = cn;
        HLEAF[gid] = f2bf(sigf(d[3]) * tanh_fast(cn));
        if (ty == 0)
            Wcol4[j] = make_float4(Wih[(size_t)j * 128 + 127],
                                   Wih[(size_t)(256 + j) * 128 + 127],
                                   Wih[(size_t)(512 + j) * 128 + 127],
                                   Wih[(size_t)(768 + j) * 128 + 127]);
    } else if (bx < 128) {
        const int gid = (bx - 64) * 256 + tid;   // Bpack (Whh only, K=256)
        const int nl  = gid & 127;
        const int seg = (gid >> 7) & 3;
        const int rest = gid >> 9;
        const int kk = rest & 7;
        const int bn = rest >> 3;
        const int g  = (nl >> 4) & 3;
        const int j  = bn * 32 + ((nl >> 6) << 4) + (nl & 15);
        const int row = g * 256 + j;
        const int k = kk * 32 + seg * 8;
        const float* src = Whh + (size_t)row * 256 + k;
        float4 w0 = *(const float4*)(src);
        float4 w1 = *(const float4*)(src + 4);
        ushort o[8] = { f2bf(w0.x), f2bf(w0.y), f2bf(w0.z), f2bf(w0.w),
                        f2bf(w1.x), f2bf(w1.y), f2bf(w1.z), f2bf(w1.w) };
        *(s8v*)(Bpack + (size_t)gid * 8) = *(const s8v*)o;
    } else {
        const int node = (bx - 128) * 256 + tid;
        if (node < 65535) {
            const int ty = nt[node];
            float corr = 0.0f;
            if (ty == 1) corr = na[node] - emb[255];
            else if (ty == 2) corr = na[node] - emb[383];
            NC[node] = make_float2((float)ty, corr);
        }
    }
}

// ================= helpers (R22-identical math) =================
__device__ __forceinline__ void gemm64_g(
    int rowbase, int nRows, int startL,
    const float2* __restrict__ NC,
    const ushort* __restrict__ h_in, const float* __restrict__ c_in,
    const ushort* __restrict__ Bpack, const float4* __restrict__ PX4,
    const float4* __restrict__ Wcol4,
    ushort (*hO)[136], float (*cO)[132])
{
    const int tid  = threadIdx.x;
    const int lane = tid & 63;
    const int wave = tid >> 6;
    const int wm2 = wave >> 2;
    const int bn  = wave & 3;
    const int lc = lane & 15, seg = lane >> 4;
    const int koff = seg * 8;

    const ushort* ph[2][2];
    #pragma unroll
    for (int mi = 0; mi < 2; ++mi) {
        int mloc = wm2 * 32 + mi * 16 + lc;
        int dg = rowbase + mloc;
        int dgc = dg < nRows ? dg : nRows - 1;
        ph[mi][0] = h_in + (size_t)(2 * dgc) * 128 + koff;
        ph[mi][1] = h_in + (size_t)(2 * dgc + 1) * 128 + koff;
    }
    const ushort* pb = Bpack + (size_t)bn * 32768 + (size_t)seg * 1024
                             + (size_t)lc * 8;

    f32x4 acc[2][8];
    #pragma unroll
    for (int mi = 0; mi < 2; ++mi)
        #pragma unroll
        for (int f = 0; f < 8; ++f) acc[mi][f] = (f32x4){0.f, 0.f, 0.f, 0.f};

    #pragma unroll
    for (int kk = 0; kk < 8; ++kk) {
        const int hi = kk >> 2, off = (kk & 3) * 32;
        s8v a0 = *(const s8v*)(ph[0][hi] + off);
        s8v a1 = *(const s8v*)(ph[1][hi] + off);
        #pragma unroll
        for (int f = 0; f < 8; ++f) {
            s8v bb = *(const s8v*)(pb + (size_t)kk * 4096 + f * 128);
            acc[0][f] = __builtin_amdgcn_mfma_f32_16x16x32_bf16(a0, bb, acc[0][f], 0, 0, 0);
            acc[1][f] = __builtin_amdgcn_mfma_f32_16x16x32_bf16(a1, bb, acc[1][f], 0, 0, 0);
        }
    }
    #pragma unroll
    for (int bh = 0; bh < 2; ++bh) {
        const int j = bn * 32 + bh * 16 + lc;
        const float4 wc = Wcol4[j];
        #pragma unroll
        for (int mi = 0; mi < 2; ++mi) {
            #pragma unroll
            for (int r = 0; r < 4; ++r) {
                const int mloc = wm2 * 32 + mi * 16 + seg * 4 + r;
                const int dg = rowbase + mloc;
                if (dg < nRows) {
                    const float2 nc = NC[startL + dg];
                    const int ty = (int)nc.x;
                    const float corr = nc.y;
                    const float4 px = PX4[(size_t)ty * 128 + j];
                    const float gi = acc[mi][bh * 4 + 0][r] + px.x + corr * wc.x;
                    const float gf = acc[mi][bh * 4 + 1][r] + px.y + corr * wc.y;
                    const float gg = acc[mi][bh * 4 + 2][r] + px.z + corr * wc.z;
                    const float go = acc[mi][bh * 4 + 3][r] + px.w + corr * wc.w;
                    const float c0 = c_in[(size_t)dg * 128 + j];
                    const float cn = sigf(gf) * c0 + sigf(gi) * tanh_fast(gg);
                    const float hn = sigf(go) * tanh_fast(cn);
                    hO[mloc][j] = f2bf(hn);
                    if (!(mloc & 1)) cO[mloc >> 1][j] = cn;
                }
            }
        }
    }
}

__device__ __forceinline__ void gemm64_l(
    int startL, int gbase,
    const float2* __restrict__ NC,
    const ushort (*hIn)[136], const float (*cIn)[132],
    const ushort* __restrict__ Bpack, const float4* __restrict__ PX4,
    const float4* __restrict__ Wcol4,
    ushort (*hO)[136], float (*cO)[132])
{
    const int tid  = threadIdx.x;
    const int lane = tid & 63;
    const int wave = tid >> 6;
    const int wm2 = wave >> 2;
    const int bn  = wave & 3;
    const int lc = lane & 15, seg = lane >> 4;
    const int koff = seg * 8;

    const int m0 = wm2 * 32 + lc;
    const int m1 = m0 + 16;
    const ushort* pb = Bpack + (size_t)bn * 32768 + (size_t)seg * 1024
                             + (size_t)lc * 8;

    f32x4 acc[2][8];
    #pragma unroll
    for (int mi = 0; mi < 2; ++mi)
        #pragma unroll
        for (int f = 0; f < 8; ++f) acc[mi][f] = (f32x4){0.f, 0.f, 0.f, 0.f};

    #pragma unroll
    for (int kk = 0; kk < 8; ++kk) {
        const int hi = kk >> 2, off = (kk & 3) * 32;
        s8v a0 = *(const s8v*)(&hIn[2 * m0 + hi][off + koff]);
        s8v a1 = *(const s8v*)(&hIn[2 * m1 + hi][off + koff]);
        #pragma unroll
        for (int f = 0; f < 8; ++f) {
            s8v bb = *(const s8v*)(pb + (size_t)kk * 4096 + f * 128);
            acc[0][f] = __builtin_amdgcn_mfma_f32_16x16x32_bf16(a0, bb, acc[0][f], 0, 0, 0);
            acc[1][f] = __builtin_amdgcn_mfma_f32_16x16x32_bf16(a1, bb, acc[1][f], 0, 0, 0);
        }
    }
    #pragma unroll
    for (int bh = 0; bh < 2; ++bh) {
        const int j = bn * 32 + bh * 16 + lc;
        const float4 wc = Wcol4[j];
        #pragma unroll
        for (int mi = 0; mi < 2; ++mi) {
            #pragma unroll
            for (int r = 0; r < 4; ++r) {
                const int mloc = wm2 * 32 + mi * 16 + seg * 4 + r;
                const float2 nc = NC[startL + gbase + mloc];
                const int ty = (int)nc.x;
                const float corr = nc.y;
                const float4 px = PX4[(size_t)ty * 128 + j];
                const float gi = acc[mi][bh * 4 + 0][r] + px.x + corr * wc.x;
                const float gf = acc[mi][bh * 4 + 1][r] + px.y + corr * wc.y;
                const float gg = acc[mi][bh * 4 + 2][r] + px.z + corr * wc.z;
                const float go = acc[mi][bh * 4 + 3][r] + px.w + corr * wc.w;
                const float c0 = cIn[mloc][j];
                const float cn = sigf(gf) * c0 + sigf(gi) * tanh_fast(gg);
                const float hn = sigf(go) * tanh_fast(cn);
                hO[mloc][j] = f2bf(hn);
                if (!(mloc & 1)) cO[mloc >> 1][j] = cn;
            }
        }
    }
}

template<int OUT>   // 0=global, 1=LDS
__device__ __forceinline__ void gemm32_l(
    int gbase, int nloc, int startL,
    const float2* __restrict__ NC,
    const ushort (*hIn)[136], const float (*cIn)[132],
    const ushort* __restrict__ Bpack, const float4* __restrict__ PX4,
    const float4* __restrict__ Wcol4,
    ushort* __restrict__ h_out, float* __restrict__ c_out,
    ushort (*hOL)[136], float (*cOL)[132])
{
    const int tid  = threadIdx.x;
    const int lane = tid & 63;
    const int wave = tid >> 6;
    const int bn = wave >> 1, wn = wave & 1;
    const int lc = lane & 15, seg = lane >> 4;
    const int koff = seg * 8;

    int mcl[2];
    #pragma unroll
    for (int mi = 0; mi < 2; ++mi) {
        int m = mi * 16 + lc;
        mcl[mi] = m < nloc ? m : nloc - 1;
    }
    const ushort* pb = Bpack + (size_t)bn * 32768 + (size_t)seg * 1024
                             + (size_t)(wn * 64 + lc) * 8;

    f32x4 acc[2][4];
    #pragma unroll
    for (int mi = 0; mi < 2; ++mi)
        #pragma unroll
        for (int f = 0; f < 4; ++f) acc[mi][f] = (f32x4){0.f, 0.f, 0.f, 0.f};

    #pragma unroll
    for (int kk = 0; kk < 8; ++kk) {
        const int hi = kk >> 2, off = (kk & 3) * 32;
        s8v a0 = *(const s8v*)(&hIn[2 * mcl[0] + hi][off + koff]);
        s8v a1 = *(const s8v*)(&hIn[2 * mcl[1] + hi][off + koff]);
        #pragma unroll
        for (int f = 0; f < 4; ++f) {
            s8v bb = *(const s8v*)(pb + (size_t)kk * 4096 + f * 128);
            acc[0][f] = __builtin_amdgcn_mfma_f32_16x16x32_bf16(a0, bb, acc[0][f], 0, 0, 0);
            acc[1][f] = __builtin_amdgcn_mfma_f32_16x16x32_bf16(a1, bb, acc[1][f], 0, 0, 0);
        }
    }

    const int j = bn * 32 + wn * 16 + lc;
    const float4 wc = Wcol4[j];
    #pragma unroll
    for (int mi = 0; mi < 2; ++mi) {
        #pragma unroll
        for (int r = 0; r < 4; ++r) {
            const int m = mi * 16 + seg * 4 + r;
            if (m < nloc) {
                const int mPg = gbase + m;
                const float2 nc = NC[startL + mPg];
                const int ty = (int)nc.x;
                const float corr = nc.y;
                const float4 px = PX4[(size_t)ty * 128 + j];
                const float gi = acc[mi][0][r] + px.x + corr * wc.x;
                const float gf = acc[mi][1][r] + px.y + corr * wc.y;
                const float gg = acc[mi][2][r] + px.z + corr * wc.z;
                const float go = acc[mi][3][r] + px.w + corr * wc.w;
                const float c0 = cIn[m][j];
                const float cn = sigf(gf) * c0 + sigf(gi) * tanh_fast(gg);
                const float hn = sigf(go) * tanh_fast(cn);
                if (OUT == 0) {
                    h_out[(size_t)mPg * 128 + j] = f2bf(hn);
                    if (!(mPg & 1)) c_out[(size_t)(mPg >> 1) * 128 + j] = cn;
                } else {
                    hOL[m][j] = f2bf(hn);
                    if (!(m & 1)) cOL[m >> 1][j] = cn;
                }
            }
        }
    }
}

// ---------------- mega1: levels 15..12, 256 blocks x 512 ----------------
__global__ __launch_bounds__(512) void mega1(
    const float2* __restrict__ NC,
    const ushort* __restrict__ Bpack, const float4* __restrict__ PX4,
    const float4* __restrict__ Wcol4,
    const ushort* __restrict__ HLEAF, const float* __restrict__ CLEAF,
    ushort* __restrict__ h_out, float* __restrict__ c_out)   // level-12
{
    __shared__ __align__(16) ushort hD[128][136];
    __shared__ float cD[64][132];
    __shared__ __align__(16) ushort hM[64][136];
    __shared__ float cM[32][132];

    const int tid = threadIdx.x;
    const int b = blockIdx.x;

    {
        const int mloc = tid >> 2;   // 0..127
        const int p4   = tid & 3;    // 32-elem chunk
        const int node = 32767 + 128 * b + mloc;
        const float2 nc = NC[node];
        const int ty = (int)nc.x;
        if (ty != 1 && ty != 2) {
            #pragma unroll
            for (int q = 0; q < 4; ++q)
                *(s8v*)(&hD[mloc][p4 * 32 + q * 8]) =
                    *(const s8v*)(HLEAF + (size_t)ty * 128 + p4 * 32 + q * 8);
            if (!(mloc & 1)) {
                const float4* cr = (const float4*)(CLEAF + (size_t)ty * 128 + p4 * 32);
                float4* cw = (float4*)(&cD[mloc >> 1][p4 * 32]);
                #pragma unroll
                for (int q = 0; q < 8; ++q) cw[q] = cr[q];
            }
        } else {
            const float corr = nc.y;
            #pragma unroll 1
            for (int q = 0; q < 32; ++q) {
                const int jj = p4 * 32 + q;
                const float4 px = PX4[(size_t)ty * 128 + jj];
                const float4 wc = Wcol4[jj];
                const float gi = px.x + corr * wc.x;
                const float gg = px.z + corr * wc.z;
                const float go = px.w + corr * wc.w;
                const float cn = sigf(gi) * tanh_fast(gg);
                const float hn = sigf(go) * tanh_fast(cn);
                hD[mloc][jj] = f2bf(hn);
                if (!(mloc & 1)) cD[mloc >> 1][jj] = cn;
            }
        }
    }
    __syncthreads();
    gemm64_l(16383, 64 * b, NC, hD, cD, Bpack, PX4, Wcol4, hM, cM);   // L14
    __syncthreads();
    gemm32_l<1>(32 * b, 32, 8191, NC, hM, cM, Bpack, PX4, Wcol4,
                nullptr, nullptr, hD, cD);                             // L13
    __syncthreads();
    gemm32_l<0>(16 * b, 16, 4095, NC, hD, cD, Bpack, PX4, Wcol4,
                h_out, c_out, nullptr, nullptr);                       // L12 -> global
}

// ---------------- mega2: levels 11..5, 32 blocks x 512 (looped stages) ----------------
__global__ __launch_bounds__(512) void mega2(
    const float2* __restrict__ NC,
    const ushort* __restrict__ Bpack, const float4* __restrict__ PX4,
    const float4* __restrict__ Wcol4,
    const ushort* __restrict__ h_in, const float* __restrict__ c_in,   // level-12
    ushort* __restrict__ h_out, float* __restrict__ c_out)             // level-5
{
    __shared__ __align__(16) ushort hD[64][136];
    __shared__ float cD[32][132];
    __shared__ __align__(16) ushort hM[32][136];
    __shared__ float cM[16][132];

    const int b = blockIdx.x;

    gemm64_g(64 * b, 2048, 2047, NC, h_in, c_in,
             Bpack, PX4, Wcol4, hD, cD);                               // L11
    // L10..L6 in a rolled loop (one gemm32_l<1> instance)
    ushort (*hi_)[136] = hD;  float (*ci_)[132] = cD;
    ushort (*ho_)[136] = hM;  float (*co_)[132] = cM;
    #pragma unroll 1
    for (int s = 0; s < 5; ++s) {
        __syncthreads();
        const int n = 32 >> s;                    // 32,16,8,4,2
        gemm32_l<1>(n * b, n, (1024 >> s) - 1, NC, hi_, ci_, Bpack, PX4, Wcol4,
                    nullptr, nullptr, ho_, co_);
        ushort (*th)[136] = hi_; hi_ = ho_; ho_ = th;
        float  (*tc)[132] = ci_; ci_ = co_; co_ = tc;
    }
    __syncthreads();
    gemm32_l<0>(b, 1, 31, NC, hi_, ci_, Bpack, PX4, Wcol4,
                h_out, c_out, nullptr, nullptr);                       // L5 -> global
}

// ---------------- mega3: levels 4..0 + MLP head, one block x 512 (looped stages) ----------------
__global__ __launch_bounds__(512) void mega3(
    const float2* __restrict__ NC,
    const ushort* __restrict__ Bpack, const float4* __restrict__ PX4,
    const float4* __restrict__ Wcol4,
    const ushort* __restrict__ h_in, const float* __restrict__ c_in,   // level-5
    const float* __restrict__ W1, const float* __restrict__ b1,
    const float* __restrict__ W2, const float* __restrict__ b2,
    const float* __restrict__ vmask, float* __restrict__ out)
{
    __shared__ __align__(16) ushort hD[64][136];
    __shared__ float cD[32][132];
    __shared__ __align__(16) ushort hM[32][136];
    __shared__ float cM[16][132];
    __shared__ float hs[128];
    __shared__ float as[128];

    const int tid = threadIdx.x;

    gemm64_g(0, 16, 15, NC, h_in, c_in, Bpack, PX4, Wcol4, hD, cD);    // L4 (16 rows)
    // L3..L0 in a rolled loop
    ushort (*hi_)[136] = hD;  float (*ci_)[132] = cD;
    ushort (*ho_)[136] = hM;  float (*co_)[132] = cM;
    #pragma unroll 1
    for (int s = 0; s < 4; ++s) {
        __syncthreads();
        const int n = 8 >> s;                     // 8,4,2,1
        gemm32_l<1>(0, n, n - 1, NC, hi_, ci_, Bpack, PX4, Wcol4,
                    nullptr, nullptr, ho_, co_);
        ushort (*th)[136] = hi_; hi_ = ho_; ho_ = th;
        float  (*tc)[132] = ci_; ci_ = co_; co_ = tc;
    }
    __syncthreads();
    if (tid < 128) hs[tid] = bf2f(hi_[0][tid]);   // root h
    __syncthreads();
    if (tid < 128) {
        float a1h = b1[tid];
        #pragma unroll 4
        for (int k = 0; k < 128; ++k) a1h = fmaf(hs[k], W1[tid * 128 + k], a1h);
        as[tid] = fmaxf(a1h, 0.0f);
    }
    __syncthreads();
    if (tid < 32) {
        float l = b2[tid];
        #pragma unroll 4
        for (int k = 0; k < 128; ++k) l = fmaf(as[k], W2[tid * 128 + k], l);
        l = (l + logf(vmask[tid])) * (1.0f / 3.0f);
        float mx = l;
        #pragma unroll
        for (int o = 16; o >= 1; o >>= 1) mx = fmaxf(mx, __shfl_xor(mx, o, 32));
        const float e = __expf(l - mx);
        float s = e;
        #pragma unroll
        for (int o = 16; o >= 1; o >>= 1) s += __shfl_xor(s, o, 32);
        out[tid] = e / s;
    }
}

extern "C" void kernel_launch(void* const* d_in, const int* in_sizes, int n_in,
                              void* d_out, int out_size, void* d_ws, size_t ws_size,
                              hipStream_t stream)
{
    const int*   node_types = (const int*)  d_in[0];
    const float* node_args  = (const float*)d_in[1];
    const float* vmask      = (const float*)d_in[2];
    const float* emb        = (const float*)d_in[3];
    const float* Wih        = (const float*)d_in[4];
    const float* Whh        = (const float*)d_in[5];
    const float* bih        = (const float*)d_in[6];
    const float* bhh        = (const float*)d_in[7];
    const float* W1         = (const float*)d_in[8];
    const float* b1         = (const float*)d_in[9];
    const float* W2         = (const float*)d_in[10];
    const float* b2         = (const float*)d_in[11];

    char* w = (char*)d_ws;
    ushort* Bpack = (ushort*)(w);                 // 262,144
    float4* PX4   = (float4*)(w + 262144);        // 262,144
    float4* Wcol4 = (float4*)(w + 524288);        // 2,048
    ushort* HLEAF = (ushort*)(w + 526336);        // 32,768
    float*  CLEAF = (float*) (w + 559104);        // 65,536
    float2* NC    = (float2*)(w + 624640);        // 524,288
    ushort* h12   = (ushort*)(w + 1148928);       // 1,048,576
    float*  c12   = (float*) (w + 2197504);       // 1,048,576
    ushort* h5    = (ushort*)(w + 3246080);       // 32*128*2 = 8,192 (slot 16,384)
    float*  c5    = (float*) (w + 3262464);       // 16*128*4 = 8,192 (slot 16,384)

    float* out = (float*)d_out;

    prepass<<<384, 256, 0, stream>>>(node_types, node_args, emb,
                                     Wih, Whh, bih, bhh,
                                     Bpack, PX4, Wcol4, HLEAF, CLEAF, NC);
    mega1<<<256, 512, 0, stream>>>(NC, Bpack, PX4, Wcol4, HLEAF, CLEAF, h12, c12);
    mega2<<<32, 512, 0, stream>>>(NC, Bpack, PX4, Wcol4, h12, c12, h5, c5);
    mega3<<<1, 512, 0, stream>>>(NC, Bpack, PX4, Wcol4, h5, c5,
                                 W1, b1, W2, b2, vmask, out);
}